// Round 12
// baseline (2939.340 us; speedup 1.0000x reference)
//
#include <hip/hip_runtime.h>
#include <hip/hip_bf16.h>

// EncoderDecoderConvLSTM — Round 22: R21 persistent 8-row blocks, slot FIX.
// R21 NaN'd: in-loop halo DMA wrote slot (py+2)&3 instead of (py+1)&3 ->
// clobbered the hr=0 slot mid-row (race) and left row y+1's hr=2 slot
// uninitialized (NaN). Fixed to (py+1)&3; all else identical to R21:
// grid (32,8), 8 rows/block; Bs = 4-slot circular row buffer; one new halo
// row DMA'd per row at phase 0 (latency hidden under 18 phases); A 3-buf
// ping-pong continuous across rows (18%3==0); waits: row ends vmcnt(0),
// j=0/1 barrier-only, j>=2 vmcnt(2)+barrier. Encoder t=0 light 1-row path;
// head fused into decoder t=1..11. h pre-swizzled ^((px+1)&7)<<3; W
// pre-swizzled ^(oc&7)<<3; zbuf border redirect.

#define HW 4096
#define NF 64

typedef __attribute__((ext_vector_type(8))) short bf16x8;
typedef __attribute__((ext_vector_type(4))) float f32x4;

__device__ __forceinline__ float fsig(float v) {
  return __builtin_amdgcn_rcpf(1.f + __expf(-v));
}
__device__ __forceinline__ float ftanh(float v) {
  float vc = fminf(fmaxf(v, -15.f), 15.f);
  float e = __expf(2.f * vc);
  return (e - 1.f) * __builtin_amdgcn_rcpf(e + 1.f);
}
__device__ __forceinline__ float bf2f(short s) {
  union { unsigned u; float f; } a;
  a.u = ((unsigned)(unsigned short)s) << 16;
  return a.f;
}
__device__ __forceinline__ short f2bf(float f) {  // RNE
  union { float f; unsigned u; } a;
  a.f = f;
  unsigned r = (a.u + 0x7fff + ((a.u >> 16) & 1)) >> 16;
  return (short)r;
}
// async 16B/lane global->LDS; lds base must be wave-uniform
__device__ __forceinline__ void dma16(const short* g, short* l) {
  __builtin_amdgcn_global_load_lds(
      (const __attribute__((address_space(1))) char*)g,
      (__attribute__((address_space(3))) char*)l, 16, 0, 0);
}

template <bool HAS_X, bool HAS_H, bool FUSE_HEAD>
__global__ __launch_bounds__(512) void lstm_mfma_k(
    const short* __restrict__ hin,   // [32][4096][64] bf16, PRE-SWIZZLED
    const short* __restrict__ W,     // [9][256][64] bf16, pre-swizzled
    const float* __restrict__ wx,    // [9][256] f32 (x-part) or null
    const float* __restrict__ xpl,   // x + t*HW (batch stride 12*HW) or null
    const float* __restrict__ bias,  // [256] f32
    const float* __restrict__ cin,   // [32][4096][64] f32 or null (c==0)
    const short* __restrict__ zbuf,  // 1 KB zeros (border rows)
    short* __restrict__ hout,        // PRE-SWIZZLED store
    float* __restrict__ cout,
    const float* __restrict__ wc2,   // [9][64] f32 (head) or null
    const float* __restrict__ bcnn,  // [1] f32 (head) or null
    float* __restrict__ yout,        // [32][12][4096] or null
    int th) {                        // head time index
  const int tid = threadIdx.x;
  if (FUSE_HEAD) {
    if (blockIdx.y >= 8) {  // ---- fused head: y[th] from hin ----
      const int f = (blockIdx.x + (blockIdx.y - 8) * 32) * 512 + tid;
      const int pix = f & 4095;
      const int b = f >> 12;
      const int x0 = pix & 63, y0 = pix >> 6;
      float acc = bcnn[0];
      const short* hb = hin + (size_t)b * (HW * 64);
#pragma unroll
      for (int tap = 0; tap < 9; ++tap) {
        const int yy = y0 + tap / 3 - 1, xx = x0 + (tap % 3) - 1;
        if (yy < 0 || yy > 63 || xx < 0 || xx > 63) continue;
        const short* hp = hb + (yy * 64 + xx) * 64;
        const int sw8 = (xx + 1) & 7;
        const float* wp = wc2 + tap * 64;
#pragma unroll
        for (int f8 = 0; f8 < 8; ++f8) {
          bf16x8 v = *reinterpret_cast<const bf16x8*>(hp + ((f8 ^ sw8) * 8));
#pragma unroll
          for (int j = 0; j < 8; ++j)
            acc = fmaf(wp[f8 * 8 + j], bf2f(v[j]), acc);
        }
      }
      yout[(size_t)(b * 12 + th) * HW + pix] = acc;
      return;
    }
  }
  const int b = blockIdx.x;        // 0..31 batch (fast dim -> XCD spread)
  const int lane = tid & 63;
  const int wv = tid >> 6;         // 0..7
  const int wnf = wv & 3;          // oc slice within each gate
  const int whalf = wv >> 2;       // 0..1 px half
  const int col = lane & 15;
  const int quad = lane >> 4;

  __shared__ short As3[3][8192];   // 3 x 16 KB gate-pair buffers
  __shared__ short Bs[4][4224];    // 4 circular halo-row slots [66 px][64 ch]
  __shared__ float xs[4][64];      // circular x rows

  if (!HAS_H) {
    // ---- light 1-row path (encoder t=0): grid (32,64), h==0, c==0 ----
    const int y = blockIdx.y;
    if (tid < 192) {
      const float* xb = xpl + (size_t)b * (12 * HW);
      const int r = tid >> 6, cx = tid & 63;
      const int py = y - 1 + r;
      xs[r][cx] = (py >= 0 && py < 64) ? xb[py * 64 + cx] : 0.f;
    }
    __syncthreads();
    f32x4 acc[4][2];
#pragma unroll
    for (int g = 0; g < 4; ++g) {
      const int oc0 = g * 64 + wnf * 16 + quad * 4;
#pragma unroll
      for (int nt = 0; nt < 2; ++nt)
#pragma unroll
        for (int r = 0; r < 4; ++r) acc[g][nt][r] = bias[oc0 + r];
    }
#pragma unroll
    for (int tap = 0; tap < 9; ++tap) {
      float xv[2];
#pragma unroll
      for (int nt = 0; nt < 2; ++nt) {
        const int pxx = whalf * 32 + nt * 16 + col + (tap % 3) - 1;
        xv[nt] = (pxx >= 0 && pxx < 64) ? xs[tap / 3][pxx] : 0.f;
      }
      const float* wt = wx + tap * 256;
#pragma unroll
      for (int g = 0; g < 4; ++g) {
        const int oc0 = g * 64 + wnf * 16 + quad * 4;
        const f32x4 w4 = *reinterpret_cast<const f32x4*>(wt + oc0);
#pragma unroll
        for (int nt = 0; nt < 2; ++nt)
#pragma unroll
          for (int r = 0; r < 4; ++r)
            acc[g][nt][r] = fmaf(xv[nt], w4[r], acc[g][nt][r]);
      }
    }
    const int nf0 = wnf * 16 + quad * 4;
#pragma unroll
    for (int nt = 0; nt < 2; ++nt) {
      const int px = whalf * 32 + nt * 16 + col;
      const int swz = ((px + 1) & 7) << 3;
      const size_t pix = (size_t)b * HW + y * 64 + px;
      f32x4 cnew;
      short hnew[4];
#pragma unroll
      for (int r = 0; r < 4; ++r) {
        float i_ = fsig(acc[0][nt][r]);
        float o_ = fsig(acc[2][nt][r]);
        float g_ = ftanh(acc[3][nt][r]);
        float cn = i_ * g_;
        cnew[r] = cn;
        hnew[r] = f2bf(o_ * ftanh(cn));
      }
      *reinterpret_cast<f32x4*>(cout + pix * 64 + nf0) = cnew;
      short4 hv = make_short4(hnew[0], hnew[1], hnew[2], hnew[3]);
      *reinterpret_cast<short4*>(hout + pix * 64 + (nf0 ^ swz)) = hv;
    }
    return;
  }

  // ================= persistent 8-row path: grid (32,8) =================
  const int y0 = blockIdx.y * 8;
  const short* hb = hin + (size_t)b * (HW * 64);
  const float* xb = HAS_X ? (xpl + (size_t)b * (12 * HW)) : nullptr;

  // ---- prologue: halo rows y0-1..y0+1 into circular slots, A phases 0,1 ----
#pragma unroll
  for (int r = 0; r < 3; ++r) {
    const int py = y0 - 1 + r;   // <= 57, only lower bound can violate
    const short* src = (py >= 0)
        ? hb + ((py * 64 + 8 * wv + (lane >> 3)) * 64 + (lane & 7) * 8)
        : zbuf + lane * 8;
    dma16(src, &Bs[(py + 1) & 3][64 + wv * 512]);
  }
#pragma unroll
  for (int k = 0; k < 2; ++k) {
    const short* src = W + k * 8192;   // tap 0, gate-pair k
    dma16(src + (wv * 64 + lane) * 8, &As3[k][wv * 64 * 8]);
    dma16(src + (512 + wv * 64 + lane) * 8, &As3[k][(512 + wv * 64) * 8]);
  }
  if (tid < 64) {  // zero px-border slots 0/65 of all 4 row slots (stay zero)
    const int rs = tid >> 4, s = ((tid >> 3) & 1) * 65, ch0 = (tid & 7) * 8;
    bf16x8 z = {0, 0, 0, 0, 0, 0, 0, 0};
    *reinterpret_cast<bf16x8*>(&Bs[rs][s * 64 + ch0]) = z;
  }
  if (HAS_X) {
    if (tid < 192) {
      const int r = tid >> 6, cx = tid & 63;
      const int py = y0 - 1 + r;
      xs[(py + 1) & 3][cx] = (py >= 0) ? xb[py * 64 + cx] : 0.f;
    }
  }
  asm volatile("s_waitcnt vmcnt(0) lgkmcnt(0)" ::: "memory");
  __builtin_amdgcn_s_barrier();

  const int axr = (col & 7) << 3;
  const int abase0 = ((wnf * 16 + col) * 64 + quad * 8) ^ axr;        // kc0
  const int abase1 = ((wnf * 16 + col) * 64 + 32 + quad * 8) ^ axr;   // kc1
  short* BsF = &Bs[0][0];

#pragma unroll 1
  for (int r = 0; r < 8; ++r) {
    const int y = y0 + r;
    f32x4 acc[4][2];
#pragma unroll
    for (int g = 0; g < 4; ++g) {
      const int oc0 = g * 64 + wnf * 16 + quad * 4;
#pragma unroll
      for (int nt = 0; nt < 2; ++nt)
#pragma unroll
        for (int q = 0; q < 4; ++q) acc[g][nt][q] = bias[oc0 + q];
    }
    if (HAS_X) {  // xs rows staged >=1 row ago (visibility via j>=2 waits)
#pragma unroll
      for (int tap = 0; tap < 9; ++tap) {
        const float* xrow = xs[(y + tap / 3) & 3];
        float xv[2];
#pragma unroll
        for (int nt = 0; nt < 2; ++nt) {
          const int pxx = whalf * 32 + nt * 16 + col + (tap % 3) - 1;
          xv[nt] = (pxx >= 0 && pxx < 64) ? xrow[pxx] : 0.f;
        }
        const float* wt = wx + tap * 256;
#pragma unroll
        for (int g = 0; g < 4; ++g) {
          const int oc0 = g * 64 + wnf * 16 + quad * 4;
          const f32x4 w4 = *reinterpret_cast<const f32x4*>(wt + oc0);
#pragma unroll
          for (int nt = 0; nt < 2; ++nt)
#pragma unroll
            for (int q = 0; q < 4; ++q)
              acc[g][nt][q] = fmaf(xv[nt], w4[q], acc[g][nt][q]);
        }
      }
    }
    const int rb[3] = {((y) & 3) * 4224, ((y + 1) & 3) * 4224,
                       ((y + 2) & 3) * 4224};
    bf16x8 bh00, bh01, bh10, bh11;  // B frags held across gate-pair phases

    // ---- 18 phases; A pipeline continues across rows ----
#pragma unroll
    for (int j = 0; j < 18; ++j) {
      const int tap = j >> 1, gp = j & 1;
      if (j == 0) {
        __builtin_amdgcn_s_barrier();  // fences prev row's buf/slot readers
        {  // prefetch halo row y+2 (zbuf if OOB) into slot (py+1)&3 = (y+3)&3
          const int py = y + 2;
          const short* srcB = (py <= 63)
              ? hb + ((py * 64 + 8 * wv + (lane >> 3)) * 64 + (lane & 7) * 8)
              : zbuf + lane * 8;
          dma16(srcB, &Bs[(py + 1) & 3][64 + wv * 512]);   // FIXED slot
          if (HAS_X) {
            const short* srcX = (py <= 63)
                ? reinterpret_cast<const short*>(xb + py * 64 + wv * 8) +
                      lane * 8
                : zbuf + lane * 8;
            if (lane < 2)
              dma16(srcX, reinterpret_cast<short*>(&xs[(py + 1) & 3][wv * 8]));
          }
        }
      } else if (j == 1) {
        __builtin_amdgcn_s_barrier();
      } else {
        asm volatile("s_waitcnt vmcnt(2)" ::: "memory");
        __builtin_amdgcn_s_barrier();
      }
      {  // issue A for phase (j+2)%18 into buf (j+2)%3 (same addrs every row)
        const int p2 = (j + 2) % 18;
        const short* src = W + (p2 >> 1) * 16384 + (p2 & 1) * 8192;
        dma16(src + (wv * 64 + lane) * 8, &As3[(j + 2) % 3][wv * 64 * 8]);
        dma16(src + (512 + wv * 64 + lane) * 8,
              &As3[(j + 2) % 3][(512 + wv * 64) * 8]);
      }
      if (gp == 0) {  // read this tap's 4 B frags once (Bs slots stable)
        const int hr = tap / 3;
        const int sb = col + tap % 3;
        const int sx = (sb & 7) << 3;
        const int o = rb[hr] + (whalf * 32 + sb) * 64;
        bh00 = *reinterpret_cast<const bf16x8*>(&BsF[(o + quad * 8) ^ sx]);
        bh01 = *reinterpret_cast<const bf16x8*>(&BsF[(o + 1024 + quad * 8) ^ sx]);
        bh10 = *reinterpret_cast<const bf16x8*>(&BsF[(o + 32 + quad * 8) ^ sx]);
        bh11 = *reinterpret_cast<const bf16x8*>(&BsF[(o + 1024 + 32 + quad * 8) ^ sx]);
      }
#pragma unroll
      for (int kc = 0; kc < 2; ++kc) {
        const bf16x8 a0 = *reinterpret_cast<const bf16x8*>(
            &As3[j % 3][kc ? abase1 : abase0]);
        const bf16x8 a1 = *reinterpret_cast<const bf16x8*>(
            &As3[j % 3][(kc ? abase1 : abase0) + 4096]);
        const bf16x8 bb0 = kc ? bh10 : bh00;
        const bf16x8 bb1 = kc ? bh11 : bh01;
        __builtin_amdgcn_s_setprio(1);
        acc[gp * 2][0] = __builtin_amdgcn_mfma_f32_16x16x32_bf16(a0, bb0, acc[gp * 2][0], 0, 0, 0);
        acc[gp * 2][1] = __builtin_amdgcn_mfma_f32_16x16x32_bf16(a0, bb1, acc[gp * 2][1], 0, 0, 0);
        acc[gp * 2 + 1][0] = __builtin_amdgcn_mfma_f32_16x16x32_bf16(a1, bb0, acc[gp * 2 + 1][0], 0, 0, 0);
        acc[gp * 2 + 1][1] = __builtin_amdgcn_mfma_f32_16x16x32_bf16(a1, bb1, acc[gp * 2 + 1][1], 0, 0, 0);
        __builtin_amdgcn_s_setprio(0);
      }
    }

    // ---- row epilogue; then drain so next row starts with clean counts ----
    const int nf0 = wnf * 16 + quad * 4;
#pragma unroll
    for (int nt = 0; nt < 2; ++nt) {
      const int px = whalf * 32 + nt * 16 + col;
      const int swz = ((px + 1) & 7) << 3;
      const size_t pix = (size_t)b * HW + y * 64 + px;
      f32x4 cold = {0.f, 0.f, 0.f, 0.f};
      if (cin) cold = *reinterpret_cast<const f32x4*>(cin + pix * 64 + nf0);
      f32x4 cnew;
      short hnew[4];
#pragma unroll
      for (int q = 0; q < 4; ++q) {
        float i_ = fsig(acc[0][nt][q]);
        float f_ = fsig(acc[1][nt][q]);
        float o_ = fsig(acc[2][nt][q]);
        float g_ = ftanh(acc[3][nt][q]);
        float cn = fmaf(f_, cold[q], i_ * g_);
        cnew[q] = cn;
        hnew[q] = f2bf(o_ * ftanh(cn));
      }
      *reinterpret_cast<f32x4*>(cout + pix * 64 + nf0) = cnew;
      short4 hv = make_short4(hnew[0], hnew[1], hnew[2], hnew[3]);
      *reinterpret_cast<short4*>(hout + pix * 64 + (nf0 ^ swz)) = hv;
    }
    asm volatile("s_waitcnt vmcnt(0)" ::: "memory");
  }
}

// standalone head (last decoder step): y[b,t,pix] from pre-swizzled h
__global__ __launch_bounds__(256) void head_k(const short* __restrict__ h,
                                              const float* __restrict__ wc2,
                                              const float* __restrict__ bc,
                                              float* __restrict__ yout, int t) {
  const int tid = blockIdx.x * 256 + threadIdx.x;  // 131072 threads
  const int pix = tid & 4095;
  const int b = tid >> 12;
  const int x0 = pix & 63, y0 = pix >> 6;
  float acc = bc[0];
  const short* hb = h + (size_t)b * (HW * 64);
#pragma unroll
  for (int tap = 0; tap < 9; ++tap) {
    const int yy = y0 + tap / 3 - 1, xx = x0 + (tap % 3) - 1;
    if (yy < 0 || yy > 63 || xx < 0 || xx > 63) continue;
    const short* hp = hb + (yy * 64 + xx) * 64;
    const int sw8 = (xx + 1) & 7;
    const float* wp = wc2 + tap * 64;
#pragma unroll
    for (int f8 = 0; f8 < 8; ++f8) {
      bf16x8 v = *reinterpret_cast<const bf16x8*>(hp + ((f8 ^ sw8) * 8));
#pragma unroll
      for (int j = 0; j < 8; ++j) acc = fmaf(wp[f8 * 8 + j], bf2f(v[j]), acc);
    }
  }
  yout[(size_t)(b * 12 + t) * HW + pix] = acc;
}

// encoder-vector output: transpose swizzled [b][pix][ch] bf16 -> [b][ch][pix] f32
__global__ __launch_bounds__(256) void ev_out_k(const short* __restrict__ h,
                                                float* __restrict__ out) {
  __shared__ float tl[64][65];
  const int b = blockIdx.y, pg = blockIdx.x;
  const int p0 = pg * 64;
  {
    const int pixl = threadIdx.x >> 2, c0 = (threadIdx.x & 3) * 16;
    const int sw8 = (pixl + 1) & 7;   // px = pixl (p0 multiple of 64)
    const short* hp = h + ((size_t)b * HW + p0 + pixl) * 64;
#pragma unroll
    for (int gi = 0; gi < 2; ++gi) {
      const int grp = (c0 >> 3) + gi;
      bf16x8 v = *reinterpret_cast<const bf16x8*>(hp + ((grp ^ sw8) * 8));
#pragma unroll
      for (int j = 0; j < 8; ++j) tl[pixl][grp * 8 + j] = bf2f(v[j]);
    }
  }
  __syncthreads();
  {
    const int ch = threadIdx.x >> 2, q0 = (threadIdx.x & 3) * 16;
    float* op = out + ((size_t)b * 64 + ch) * (size_t)HW + p0 + q0;
#pragma unroll
    for (int i = 0; i < 16; ++i) op[i] = tl[q0 + i][ch];
  }
}

// W_enc [256][65][3][3] f32 -> Wh bf16 [9][256][64] SWIZZLED (^(oc&7)<<3)
// + wx f32 [9][256] (tap-major for vectorized f32x4 loads)
__global__ __launch_bounds__(256) void reo_enc_k(const float* __restrict__ src,
                                                 short* __restrict__ Wh,
                                                 float* __restrict__ wx) {
  const int idx = blockIdx.x * 256 + threadIdx.x;
  if (idx < 9 * 256 * 64) {
    const int tap = idx >> 14, oc = (idx >> 6) & 255, c = idx & 63;
    const int dst = tap * 16384 + (((oc * 64) + c) ^ ((oc & 7) << 3));
    Wh[dst] = f2bf(src[(oc * 65 + (c + 1)) * 9 + tap]);
  }
  if (idx < 256 * 9) {
    const int tap = idx >> 8, oc = idx & 255;  // wx[tap][oc]
    wx[idx] = src[(oc * 65 + 0) * 9 + tap];
  }
}

// W_dec [256][128][3][3] f32 -> Wx bf16 [9][256][64], Wsum bf16, both swizzled
__global__ __launch_bounds__(256) void reo_dec_k(const float* __restrict__ src,
                                                 short* __restrict__ Wx,
                                                 short* __restrict__ Ws) {
  const int idx = blockIdx.x * 256 + threadIdx.x;
  if (idx >= 9 * 256 * 64) return;
  const int tap = idx >> 14, oc = (idx >> 6) & 255, c = idx & 63;
  const int dst = tap * 16384 + (((oc * 64) + c) ^ ((oc & 7) << 3));
  const float a = src[(oc * 128 + c) * 9 + tap];
  const float b = src[(oc * 128 + 64 + c) * 9 + tap];
  Wx[dst] = f2bf(a);
  Ws[dst] = f2bf(a + b);
}

// W_cnn [64][9] f32 -> [9][64] f32
__global__ __launch_bounds__(256) void reo_cnn_k(const float* __restrict__ src,
                                                 float* __restrict__ wc2) {
  const int idx = blockIdx.x * 256 + threadIdx.x;
  if (idx >= 576) return;
  wc2[idx] = src[(idx % 64) * 9 + (idx / 64)];
}

extern "C" void kernel_launch(void* const* d_in, const int* in_sizes, int n_in,
                              void* d_out, int out_size, void* d_ws, size_t ws_size,
                              hipStream_t stream) {
  const float* x = (const float*)d_in[0];       // [32,12,1,64,64] f32
  const float* W_enc = (const float*)d_in[2];
  const float* b_enc = (const float*)d_in[3];
  const float* W_dec = (const float*)d_in[4];
  const float* b_dec = (const float*)d_in[5];
  const float* W_cnn = (const float*)d_in[6];
  const float* b_cnn = (const float*)d_in[7];
  float* out = (float*)d_out;
  float* out_y = out;                 // [32][12][4096]
  float* out_ev = out + 1572864;      // [32][64][4096]

  float* ws = (float*)d_ws;
  float* cA = ws;                                // 8388608 f
  float* cB = cA + 8388608;                      // 8388608 f
  short* hA = (short*)(cB + 8388608);            // 8388608 sh
  short* hB = hA + 8388608;                      // 8388608 sh
  short* WEh = hB + 8388608;                     // 147456 sh
  short* WDx = WEh + 147456;                     // 147456 sh
  short* WDs = WDx + 147456;                     // 147456 sh
  float* wx = (float*)(WDs + 147456);            // 2304 f
  float* wc2 = wx + 2304;                        // 576 f
  short* zb = (short*)(wc2 + 576);               // 512 sh zeros (~101 MB total)

  reo_enc_k<<<(147456 + 255) / 256, 256, 0, stream>>>(W_enc, WEh, wx);
  reo_dec_k<<<(147456 + 255) / 256, 256, 0, stream>>>(W_dec, WDx, WDs);
  reo_cnn_k<<<3, 256, 0, stream>>>(W_cnn, wc2);
  hipMemsetAsync(zb, 0, 512 * sizeof(short), stream);

  dim3 blkL(512);
  dim3 gridT0(32, 64);   // light path: 1 row/block
  dim3 gridP(32, 8);     // persistent: 8 rows/block, 256 blocks
  dim3 gridF(32, 16);    // persistent + 256 fused-head blocks
  dim3 gridE(64, 32), blkE(256);

  // ---- encoder t=0: h==0, c==0 -> x-part only ----
  lstm_mfma_k<true, false, false><<<gridT0, blkL, 0, stream>>>(
      nullptr, WEh, wx, x, b_enc, nullptr, zb, hB, cB,
      nullptr, nullptr, nullptr, 0);
  short *ha = hB, *hb = hA;
  float *ca = cB, *cb = cA;

  // ---- encoder t=1..11 ----
  for (int t = 1; t < 12; ++t) {
    lstm_mfma_k<true, true, false><<<gridP, blkL, 0, stream>>>(
        ha, WEh, wx, x + t * HW, b_enc, ca, zb, hb, cb,
        nullptr, nullptr, nullptr, 0);
    { short* tm = ha; ha = hb; hb = tm; }
    { float* tm = ca; ca = cb; cb = tm; }
  }
  // ha = h_enc (swizzled) -> output 1 (un-swizzled transpose to [b][ch][pix])
  ev_out_k<<<gridE, blkE, 0, stream>>>(ha, out_ev);

  // ---- decoder t=0: c==0 via cin=null ----
  lstm_mfma_k<false, true, false><<<gridP, blkL, 0, stream>>>(
      ha, WDx, nullptr, nullptr, b_dec, nullptr, zb, hb, cb,
      nullptr, nullptr, nullptr, 0);
  { short* tm = ha; ha = hb; hb = tm; }
  { float* tm = ca; ca = cb; cb = tm; }

  // ---- decoder t=1..11, head(outs[t-1]) fused (reads hin) ----
  for (int t = 1; t < 12; ++t) {
    lstm_mfma_k<false, true, true><<<gridF, blkL, 0, stream>>>(
        ha, WDs, nullptr, nullptr, b_dec, ca, zb, hb, cb,
        wc2, b_cnn, out_y, t - 1);
    { short* tm = ha; ha = hb; hb = tm; }
    { float* tm = ca; ca = cb; cb = tm; }
  }
  // ---- final head on outs[11] ----
  head_k<<<512, 256, 0, stream>>>(ha, wc2, b_cnn, out_y, 11);
}